// Round 4
// baseline (162.683 us; speedup 1.0000x reference)
//
#include <hip/hip_runtime.h>

#define G 1024
#define SCALEF 1048576.0f         // 2^20 fixed-point for the sum (exact decode, absmax ~4e-6)
#define CNT_SHIFT 42              // block cell (u64): count [42..63], biased sum [0..41]
#define ELEM_BIAS (1 << 24)       // per-element bias (> max |vf|, |v| < 16)
#define LOW_MASK ((1ULL << CNT_SHIFT) - 1)
#define GCNT_SHIFT 44             // global cell (u64): count [44..63], biased sum below
#define GSUM_BIAS (1ll << 23)     // per-count bias (>= max per-element |vf|, |v| < 8)
#define GLOW_MASK ((1ULL << GCNT_SHIFT) - 1)
#define NREP 64                   // sum-fold replicas: 1024 blocks / 64 -> depth 16 per address
#define NREP_MM 8                 // min/max replicas (rare-path traffic is tiny)

// Order-preserving map float -> uint32 (monotone): uint min/max == float min/max.
__device__ __forceinline__ unsigned omap(float x) {
    unsigned u = __float_as_uint(x);
    return (u & 0x80000000u) ? ~u : (u | 0x80000000u);
}
__device__ __forceinline__ float ounmap(unsigned o) {
    unsigned u = (o & 0x80000000u) ? (o & 0x7fffffffu) : ~o;
    return __uint_as_float(u);
}

// Phase 1: warm pass, min/max ONLY, on the first 1/16 slice (~1024 samples/key).
// Ungated fire-and-forget LDS atomics; establishes per-key min/max for the gates.
__global__ __launch_bounds__(256) void gb_warm(
    const int4* __restrict__ keys, const float4* __restrict__ vals, int n4w,
    unsigned* __restrict__ rmaxo, unsigned* __restrict__ rminv)
{
    __shared__ unsigned s_mn[G];
    __shared__ unsigned s_mx[G];
    for (int k = threadIdx.x; k < G; k += 256) { s_mn[k] = 0xffffffffu; s_mx[k] = 0u; }
    __syncthreads();

    const int stride = gridDim.x * 256;
    for (int i = blockIdx.x * 256 + threadIdx.x; i < n4w; i += stride) {
        int4 k4 = keys[i]; float4 v4 = vals[i];
        unsigned o;
        o = omap(v4.x); atomicMin(&s_mn[k4.x], o); atomicMax(&s_mx[k4.x], o);
        o = omap(v4.y); atomicMin(&s_mn[k4.y], o); atomicMax(&s_mx[k4.y], o);
        o = omap(v4.z); atomicMin(&s_mn[k4.z], o); atomicMax(&s_mx[k4.z], o);
        o = omap(v4.w); atomicMin(&s_mn[k4.w], o); atomicMax(&s_mx[k4.w], o);
    }
    __syncthreads();

    const int r = blockIdx.x & (NREP_MM - 1);
    for (int k = threadIdx.x; k < G; k += 256) {
        const unsigned mn = s_mn[k], mx = s_mx[k];
        if (mn != 0xffffffffu) atomicMax(&rminv[r * G + k], ~mn);  // min inverted, id 0
        if (mx != 0u)          atomicMax(&rmaxo[r * G + k], mx);
    }
}

// Phase 2: scalar thresholds. T_min = max_k(warm min_k): skipping o > T_min is
// safe for EVERY key (o cannot beat any key's recorded min; main covers all
// elements so each key's true min always fires). T_max symmetric. Keys with no
// warm sample leave identities -> gates disable themselves (safe).
__global__ __launch_bounds__(1024) void gb_gate(
    const unsigned* __restrict__ rmaxo, const unsigned* __restrict__ rminv,
    unsigned* __restrict__ gate2)
{
    const int k = threadIdx.x;
    unsigned mx = 0u, mv = 0u;
    for (int r = 0; r < NREP_MM; ++r) {
        mx = max(mx, rmaxo[r * G + k]);
        mv = max(mv, rminv[r * G + k]);
    }
    __shared__ unsigned l_tmin[1024];
    __shared__ unsigned l_tmax[1024];
    l_tmin[k] = ~mv;   // per-key recorded min (omap); empty -> 0xffffffff
    l_tmax[k] = mx;    // per-key recorded max (omap); empty -> 0
    __syncthreads();
    for (int s = 512; s > 0; s >>= 1) {
        if (k < s) {
            l_tmin[k] = max(l_tmin[k], l_tmin[k + s]);
            l_tmax[k] = min(l_tmax[k], l_tmax[k + s]);
        }
        __syncthreads();
    }
    if (k == 0) { gate2[0] = l_tmin[0]; gate2[1] = l_tmax[0]; }
}

// Phase 3: main pass, full range. Per element: 2 register compares + 1
// fire-and-forget ds_add_u64 (packed sum+count). Rare (<1%/side) min/max
// candidates hit LDS atomics (NOT global -> no vmcnt drain in the loop).
// The LDS atomic pipe is the measured wall (R1/R3 ~48us at 3 atomics/elem,
// VALU 10%, HBM 22%); gating min/max cuts DS work ~2.3x.
__global__ __launch_bounds__(512) void gb_main(
    const int4* __restrict__ keys, const float4* __restrict__ vals, int n4,
    unsigned long long* __restrict__ racc,
    unsigned* __restrict__ rmaxo, unsigned* __restrict__ rminv,
    const unsigned* __restrict__ gate2)
{
    __shared__ unsigned long long s_sc[G];
    __shared__ unsigned s_mn[G];
    __shared__ unsigned s_mx[G];
    for (int k = threadIdx.x; k < G; k += 512) {
        s_sc[k] = 0ull; s_mn[k] = 0xffffffffu; s_mx[k] = 0u;
    }
    const unsigned Tmin = gate2[0];
    const unsigned Tmax = gate2[1];
    __syncthreads();

#define MAIN_ELEM(KK, VV)                                                      \
        {                                                                      \
            const int mk = (KK); const float mv = (VV);                        \
            const unsigned o = omap(mv);                                       \
            if (o <= Tmin) atomicMin(&s_mn[mk], o);                            \
            if (o >= Tmax) atomicMax(&s_mx[mk], o);                            \
            const int vf = __float2int_rn(mv * SCALEF);                        \
            atomicAdd(&s_sc[mk], (1ULL << CNT_SHIFT) +                         \
                      (unsigned long long)(unsigned)(vf + ELEM_BIAS));         \
        }

    const int tid    = blockIdx.x * 512 + threadIdx.x;
    const int stride = gridDim.x * 512;

    if (n4 == (stride << 3)) {
        // Fast path: every thread owns exactly 8 grid-strided int4/float4 pairs.
        int4   kb[8];
        float4 vb[8];
#pragma unroll
        for (int j = 0; j < 8; ++j) kb[j] = keys[tid + j * stride];
#pragma unroll
        for (int j = 0; j < 8; ++j) vb[j] = vals[tid + j * stride];
#pragma unroll
        for (int j = 0; j < 8; ++j) {
            MAIN_ELEM(kb[j].x, vb[j].x) MAIN_ELEM(kb[j].y, vb[j].y)
            MAIN_ELEM(kb[j].z, vb[j].z) MAIN_ELEM(kb[j].w, vb[j].w)
        }
    } else {
        // Generic fallback: 1-deep prefetch grid-stride loop.
        int i = tid;
        if (i < n4) {
            int4 k4 = keys[i]; float4 v4 = vals[i];
            for (i += stride; ; i += stride) {
                const bool more = (i < n4);
                int4 nk; float4 nv;
                if (more) { nk = keys[i]; nv = vals[i]; }
                MAIN_ELEM(k4.x, v4.x) MAIN_ELEM(k4.y, v4.y)
                MAIN_ELEM(k4.z, v4.z) MAIN_ELEM(k4.w, v4.w)
                if (!more) break;
                k4 = nk; v4 = nv;
            }
        }
    }
#undef MAIN_ELEM
    __syncthreads();

    // Fold: block cell n = cell>>42, s = (cell&mask) - n*2^24 (exact).
    // Global cell: n*2^44 + (s + n*2^23); per-element |vf| < 2^23 so the low
    // field stays non-negative and additive; totals << 2^44. Exact.
    // Min/max cells untouched by the gate keep identities -> skip.
    const int r  = blockIdx.x & (NREP - 1);
    const int rm = blockIdx.x & (NREP_MM - 1);
    unsigned long long* __restrict__ racc_r  = racc  + (size_t)r  * G;
    unsigned*           __restrict__ rmaxo_r = rmaxo + (size_t)rm * G;
    unsigned*           __restrict__ rminv_r = rminv + (size_t)rm * G;
    for (int k = threadIdx.x; k < G; k += 512) {
        const unsigned long long cell = s_sc[k];
        const unsigned n = (unsigned)(cell >> CNT_SHIFT);
        if (n) {
            const long long s = (long long)(cell & LOW_MASK) - ((long long)n << 24);
            atomicAdd(&racc_r[k],
                      ((unsigned long long)n << GCNT_SHIFT) +
                      (unsigned long long)(s + (long long)n * GSUM_BIAS));
        }
        const unsigned mxv = s_mx[k];
        const unsigned mnv = ~s_mn[k];
        if (mxv) atomicMax(&rmaxo_r[k], mxv);
        if (mnv) atomicMax(&rminv_r[k], mnv);   // min inverted, identity 0
    }
}

// Phase 4: reduce the replicas, write the 5 float32 outputs.
// gid = 1023 - key  =>  slot g = 1023 - k, key_out[g] = k.
__global__ __launch_bounds__(256) void gb_write(
    const unsigned long long* __restrict__ racc,
    const unsigned* __restrict__ rmaxo, const unsigned* __restrict__ rminv,
    float* __restrict__ out)
{
    const int k = blockIdx.x * 256 + threadIdx.x;
    unsigned long long cell = 0ull;
    for (int r = 0; r < NREP; ++r) cell += racc[r * G + k];
    unsigned mx = 0u, mv = 0u;
    for (int r = 0; r < NREP_MM; ++r) {
        mx = max(mx, rmaxo[r * G + k]);
        mv = max(mv, rminv[r * G + k]);
    }
    const unsigned n = (unsigned)(cell >> GCNT_SHIFT);
    const long long s = (long long)(cell & GLOW_MASK) - (long long)n * GSUM_BIAS;
    const float sum = (float)((double)s * (1.0 / (double)SCALEF));
    const int g = (G - 1) - k;
    out[g]         = (float)k;
    out[G + g]     = sum;
    out[2 * G + g] = sum / (float)n;
    out[3 * G + g] = ounmap(~mv);
    out[4 * G + g] = ounmap(mx);
}

extern "C" void kernel_launch(void* const* d_in, const int* in_sizes, int n_in,
                              void* d_out, int out_size, void* d_ws, size_t ws_size,
                              hipStream_t stream) {
    const int4*   keys = (const int4*)d_in[0];
    const float4* vals = (const float4*)d_in[1];
    const int n   = in_sizes[0];
    const int n4  = n / 4;
    int n4w = n4 >> 4;                  // warm slice = first 1/16 (min/max only)
    if (n4w < 1)  n4w = (n4 < 1) ? 0 : n4;
    if (n4w > n4) n4w = n4;

    // Workspace: racc u64[64][G] (512KB) | rmaxo u32[8][G] | rminv u32[8][G] | gate2
    unsigned long long* racc  = (unsigned long long*)d_ws;
    unsigned*           rmaxo = (unsigned*)(racc + (size_t)NREP * G);
    unsigned*           rminv = rmaxo + (size_t)NREP_MM * G;
    unsigned*           gate2 = rminv + (size_t)NREP_MM * G;
    const size_t acc_bytes = (size_t)NREP * G * 8 + 2 * (size_t)NREP_MM * G * 4
                           + 2 * sizeof(unsigned);

    hipMemsetAsync(d_ws, 0, acc_bytes, stream);

    hipLaunchKernelGGL(gb_warm, dim3(512), dim3(256), 0, stream,
                       keys, vals, n4w, rmaxo, rminv);
    hipLaunchKernelGGL(gb_gate, dim3(1), dim3(1024), 0, stream,
                       rmaxo, rminv, gate2);
    hipLaunchKernelGGL(gb_main, dim3(1024), dim3(512), 0, stream,
                       keys, vals, n4, racc, rmaxo, rminv, gate2);
    hipLaunchKernelGGL(gb_write, dim3(G / 256), dim3(256), 0, stream,
                       racc, rmaxo, rminv, (float*)d_out);
}

// Round 5
// 161.165 us; speedup vs baseline: 1.0094x; 1.0094x over previous
//
#include <hip/hip_runtime.h>

#define G 1024
#define SCALEF 1048576.0f         // 2^20 fixed-point for the sum (exact decode, absmax ~4e-6)
#define BIASF  8388608.0f         // 2^23 per-element bias folded into the fmaf rounding
#define GCNT_SHIFT 44             // global cell (u64): count [44..63], biased sum [0..43]
#define GSUM_BIAS (1ll << 23)     // per-count bias (matches BIASF)
#define GLOW_MASK ((1ULL << GCNT_SHIFT) - 1)
#define NREP 64                   // sum-fold replicas: 1024 blocks / 64 -> depth 16 per address
#define NREP_MM 32                // min/max replicas: depth 32 per address

// Order-preserving map float -> uint32 (monotone): uint min/max == float min/max.
__device__ __forceinline__ unsigned omap(float x) {
    unsigned u = __float_as_uint(x);
    return (u & 0x80000000u) ? ~u : (u | 0x80000000u);
}
__device__ __forceinline__ float ounmap(unsigned o) {
    unsigned u = (o & 0x80000000u) ? (o & 0x7fffffffu) : ~o;
    return __uint_as_float(u);
}

// Single main pass.
//
// R5 finding: ds_add_u64 is lane-serialized (~100 cy/wave-instr) and was the
// wall in ALL prior rounds (model fits R0/R1/R3/R4 within 1us). u32 LDS
// atomics are ~6 cy. So: split the packed sum+count u64 atomic into TWO u32
// atomics (biased sum, count). Per element: 4 cheap u32 LDS atomics, no
// global ops, no u64 DS ops. DS pipe drops from ~100K cy/CU to ~25K; the
// wall moves to memory (~50K cy).
//
// Sum exactness: per element we accumulate round(v*2^20) + 2^23 via one fmaf
// (ulp<=1 in [2^23,2^24) -> the fp32 rounding IS round-to-nearest-integer;
// error <= 0.5/2^20 per element, same as before). Per-block-per-key count is
// ~16 (Poisson, max ~60); 60*(2^23+6.3e6) << 2^32 -> u32 never overflows.
__global__ __launch_bounds__(512) void gb_main(
    const int4* __restrict__ keys, const float4* __restrict__ vals, int n4,
    unsigned long long* __restrict__ racc,
    unsigned* __restrict__ rmaxo, unsigned* __restrict__ rminv)
{
    __shared__ unsigned s_sum[G];
    __shared__ unsigned s_cnt[G];
    __shared__ unsigned s_mn[G];
    __shared__ unsigned s_mx[G];
    for (int k = threadIdx.x; k < G; k += 512) {
        s_sum[k] = 0u; s_cnt[k] = 0u; s_mn[k] = 0xffffffffu; s_mx[k] = 0u;
    }
    __syncthreads();

#define MAIN_ELEM(KK, VV)                                                      \
        {                                                                      \
            const int mk = (KK); const float mv = (VV);                        \
            const unsigned o = omap(mv);                                       \
            atomicMin(&s_mn[mk], o);                                           \
            atomicMax(&s_mx[mk], o);                                           \
            const unsigned b = (unsigned)__float2int_rn(fmaf(mv, SCALEF, BIASF)); \
            atomicAdd(&s_sum[mk], b);                                          \
            atomicAdd(&s_cnt[mk], 1u);                                         \
        }

    const int tid    = blockIdx.x * 512 + threadIdx.x;
    const int stride = gridDim.x * 512;

    if (n4 == (stride << 3)) {
        // Fast path: every thread owns exactly 8 grid-strided int4/float4 pairs.
        int4   kb[8];
        float4 vb[8];
#pragma unroll
        for (int j = 0; j < 8; ++j) kb[j] = keys[tid + j * stride];
#pragma unroll
        for (int j = 0; j < 8; ++j) vb[j] = vals[tid + j * stride];
#pragma unroll
        for (int j = 0; j < 8; ++j) {
            MAIN_ELEM(kb[j].x, vb[j].x) MAIN_ELEM(kb[j].y, vb[j].y)
            MAIN_ELEM(kb[j].z, vb[j].z) MAIN_ELEM(kb[j].w, vb[j].w)
        }
    } else {
        // Generic fallback: 1-deep prefetch grid-stride loop.
        int i = tid;
        if (i < n4) {
            int4 k4 = keys[i]; float4 v4 = vals[i];
            for (i += stride; ; i += stride) {
                const bool more = (i < n4);
                int4 nk; float4 nv;
                if (more) { nk = keys[i]; nv = vals[i]; }
                MAIN_ELEM(k4.x, v4.x) MAIN_ELEM(k4.y, v4.y)
                MAIN_ELEM(k4.z, v4.z) MAIN_ELEM(k4.w, v4.w)
                if (!more) break;
                k4 = nk; v4 = nv;
            }
        }
    }
#undef MAIN_ELEM
    __syncthreads();

    // Fold into replicated global cells. Low field accumulates the biased sum
    // directly: sum_biased = sum(vf) + n*2^23, so the global cell is just
    // (n << 44) + sum_biased. Totals: |sum(vf)| < 2^37, n*2^23 < 2^38 << 2^44.
    const int r  = blockIdx.x & (NREP - 1);
    const int rm = blockIdx.x & (NREP_MM - 1);
    unsigned long long* __restrict__ racc_r  = racc  + (size_t)r  * G;
    unsigned*           __restrict__ rmaxo_r = rmaxo + (size_t)rm * G;
    unsigned*           __restrict__ rminv_r = rminv + (size_t)rm * G;
    for (int k = threadIdx.x; k < G; k += 512) {
        const unsigned n = s_cnt[k];
        if (n) {
            atomicAdd(&racc_r[k],
                      ((unsigned long long)n << GCNT_SHIFT) +
                      (unsigned long long)s_sum[k]);
        }
        const unsigned mxv = s_mx[k];
        const unsigned mnv = ~s_mn[k];
        if (mxv) atomicMax(&rmaxo_r[k], mxv);
        if (mnv) atomicMax(&rminv_r[k], mnv);   // min inverted, identity 0
    }
}

// Reduce the replicas, write the 5 float32 outputs.
// gid = 1023 - key  =>  slot g = 1023 - k, key_out[g] = k.
__global__ __launch_bounds__(256) void gb_write(
    const unsigned long long* __restrict__ racc,
    const unsigned* __restrict__ rmaxo, const unsigned* __restrict__ rminv,
    float* __restrict__ out)
{
    const int k = blockIdx.x * 256 + threadIdx.x;
    unsigned long long cell = 0ull;
    for (int r = 0; r < NREP; ++r) cell += racc[r * G + k];
    unsigned mx = 0u, mv = 0u;
    for (int r = 0; r < NREP_MM; ++r) {
        mx = max(mx, rmaxo[r * G + k]);
        mv = max(mv, rminv[r * G + k]);
    }
    const unsigned n = (unsigned)(cell >> GCNT_SHIFT);
    const long long s = (long long)(cell & GLOW_MASK) - (long long)n * GSUM_BIAS;
    const float sum = (float)((double)s * (1.0 / (double)SCALEF));
    const int g = (G - 1) - k;
    out[g]         = (float)k;
    out[G + g]     = sum;
    out[2 * G + g] = sum / (float)n;
    out[3 * G + g] = ounmap(~mv);
    out[4 * G + g] = ounmap(mx);
}

extern "C" void kernel_launch(void* const* d_in, const int* in_sizes, int n_in,
                              void* d_out, int out_size, void* d_ws, size_t ws_size,
                              hipStream_t stream) {
    const int4*   keys = (const int4*)d_in[0];
    const float4* vals = (const float4*)d_in[1];
    const int n  = in_sizes[0];
    const int n4 = n / 4;

    // Workspace: racc u64[64][G] (512KB) | rmaxo u32[32][G] (128KB) | rminv u32[32][G] (128KB)
    unsigned long long* racc  = (unsigned long long*)d_ws;
    unsigned*           rmaxo = (unsigned*)(racc + (size_t)NREP * G);
    unsigned*           rminv = rmaxo + (size_t)NREP_MM * G;
    const size_t acc_bytes = (size_t)NREP * G * 8 + 2 * (size_t)NREP_MM * G * 4;

    hipMemsetAsync(d_ws, 0, acc_bytes, stream);

    hipLaunchKernelGGL(gb_main, dim3(1024), dim3(512), 0, stream,
                       keys, vals, n4, racc, rmaxo, rminv);
    hipLaunchKernelGGL(gb_write, dim3(G / 256), dim3(256), 0, stream,
                       racc, rmaxo, rminv, (float*)d_out);
}

// Round 6
// 160.092 us; speedup vs baseline: 1.0162x; 1.0067x over previous
//
#include <hip/hip_runtime.h>

#define G 1024
#define SCALEF 1048576.0f         // 2^20 fixed-point for the sum (exact decode, absmax ~4e-6)
#define CNT_SHIFT 42              // block cell (u64): count [42..63], biased sum [0..41]
#define ELEM_BIAS (1 << 24)       // per-element bias (> max |vf|, |v| < 16)
#define LOW_MASK ((1ULL << CNT_SHIFT) - 1)
#define GCNT_SHIFT 44             // global cell (u64): count [44..63], biased sum below
#define GSUM_BIAS (1ll << 23)     // per-count bias (>= max per-element |vf|, |v| < 8)
#define GLOW_MASK ((1ULL << GCNT_SHIFT) - 1)
#define NREP 64                   // sum-fold replicas: 2048 blocks / 64 -> depth 32 per address
#define NREP_MM 8                 // min/max replicas (rare-path traffic is tiny)

// Order-preserving map float -> uint32 (monotone): uint min/max == float min/max.
__device__ __forceinline__ unsigned omap(float x) {
    unsigned u = __float_as_uint(x);
    return (u & 0x80000000u) ? ~u : (u | 0x80000000u);
}
__device__ __forceinline__ float ounmap(unsigned o) {
    unsigned u = (o & 0x80000000u) ? (o & 0x7fffffffu) : ~o;
    return __uint_as_float(u);
}

// Phase 1: warm pass, min/max ONLY, on the first 1/16 slice (~1024 samples/key).
__global__ __launch_bounds__(256) void gb_warm(
    const int4* __restrict__ keys, const float4* __restrict__ vals, int n4w,
    unsigned* __restrict__ rmaxo, unsigned* __restrict__ rminv)
{
    __shared__ unsigned s_mn[G];
    __shared__ unsigned s_mx[G];
    for (int k = threadIdx.x; k < G; k += 256) { s_mn[k] = 0xffffffffu; s_mx[k] = 0u; }
    __syncthreads();

    const int stride = gridDim.x * 256;
    for (int i = blockIdx.x * 256 + threadIdx.x; i < n4w; i += stride) {
        int4 k4 = keys[i]; float4 v4 = vals[i];
        unsigned o;
        o = omap(v4.x); atomicMin(&s_mn[k4.x], o); atomicMax(&s_mx[k4.x], o);
        o = omap(v4.y); atomicMin(&s_mn[k4.y], o); atomicMax(&s_mx[k4.y], o);
        o = omap(v4.z); atomicMin(&s_mn[k4.z], o); atomicMax(&s_mx[k4.z], o);
        o = omap(v4.w); atomicMin(&s_mn[k4.w], o); atomicMax(&s_mx[k4.w], o);
    }
    __syncthreads();

    const int r = blockIdx.x & (NREP_MM - 1);
    for (int k = threadIdx.x; k < G; k += 256) {
        const unsigned mn = s_mn[k], mx = s_mx[k];
        if (mn != 0xffffffffu) atomicMax(&rminv[r * G + k], ~mn);  // min inverted, id 0
        if (mx != 0u)          atomicMax(&rmaxo[r * G + k], mx);
    }
}

// Phase 2: scalar thresholds. T_min = max_k(warm min_k): skipping o > T_min is
// safe for EVERY key (o cannot beat any key's recorded min; main covers all
// elements so each key's true min always fires). T_max symmetric. Keys with no
// warm sample leave identities -> gates disable themselves (safe).
__global__ __launch_bounds__(1024) void gb_gate(
    const unsigned* __restrict__ rmaxo, const unsigned* __restrict__ rminv,
    unsigned* __restrict__ gate2)
{
    const int k = threadIdx.x;
    unsigned mx = 0u, mv = 0u;
    for (int r = 0; r < NREP_MM; ++r) {
        mx = max(mx, rmaxo[r * G + k]);
        mv = max(mv, rminv[r * G + k]);
    }
    __shared__ unsigned l_tmin[1024];
    __shared__ unsigned l_tmax[1024];
    l_tmin[k] = ~mv;   // per-key recorded min (omap); empty -> 0xffffffff
    l_tmax[k] = mx;    // per-key recorded max (omap); empty -> 0
    __syncthreads();
    for (int s = 512; s > 0; s >>= 1) {
        if (k < s) {
            l_tmin[k] = max(l_tmin[k], l_tmin[k + s]);
            l_tmax[k] = min(l_tmax[k], l_tmax[k + s]);
        }
        __syncthreads();
    }
    if (k == 0) { gate2[0] = l_tmin[0]; gate2[1] = l_tmax[0]; }
}

// Phase 3: main pass (R4 body = best measured, 43.4us). R6 change: rotating
// 4-deep software pipeline (refill load for pair j+4 issues BEFORE processing
// pair j -> memory stays in flight interleaved with DS work) + 2048x256 grid
// (8 blocks/CU, smoother tail). Per element: 2 register compares, rare gated
// LDS min/max, 1 fire-and-forget ds_add_u64. Exact fixed-point sum (R4 path).
__global__ __launch_bounds__(256) void gb_main(
    const int4* __restrict__ keys, const float4* __restrict__ vals, int n4,
    unsigned long long* __restrict__ racc,
    unsigned* __restrict__ rmaxo, unsigned* __restrict__ rminv,
    const unsigned* __restrict__ gate2)
{
    __shared__ unsigned long long s_sc[G];
    __shared__ unsigned s_mn[G];
    __shared__ unsigned s_mx[G];
    const unsigned Tmin = gate2[0];
    const unsigned Tmax = gate2[1];
    for (int k = threadIdx.x; k < G; k += 256) {
        s_sc[k] = 0ull; s_mn[k] = 0xffffffffu; s_mx[k] = 0u;
    }
    __syncthreads();

#define MAIN_ELEM(KK, VV)                                                      \
        {                                                                      \
            const int mk = (KK); const float mv = (VV);                        \
            const unsigned o = omap(mv);                                       \
            if (o <= Tmin) atomicMin(&s_mn[mk], o);                            \
            if (o >= Tmax) atomicMax(&s_mx[mk], o);                            \
            const int vf = __float2int_rn(mv * SCALEF);                        \
            atomicAdd(&s_sc[mk], (1ULL << CNT_SHIFT) +                         \
                      (unsigned long long)(unsigned)(vf + ELEM_BIAS));         \
        }

    const int tid    = blockIdx.x * 256 + threadIdx.x;
    const int stride = gridDim.x * 256;

    if (n4 == (stride << 3)) {
        // Fast path: thread owns exactly 8 grid-strided pairs. Rotating 4-slot
        // pipeline; after full unroll every kb/vb index is compile-time
        // (no scratch, rule: runtime-indexed vectors spill). While processing
        // pair j, pairs j+1..j+4 are in flight (~8 loads/wave continuously).
        int4   kb[4];
        float4 vb[4];
#pragma unroll
        for (int j = 0; j < 4; ++j) { kb[j] = keys[tid + j * stride];
                                      vb[j] = vals[tid + j * stride]; }
#pragma unroll
        for (int j = 0; j < 8; ++j) {
            const int s = j & 3;
            const int4   k4 = kb[s];
            const float4 v4 = vb[s];
            if (j + 4 < 8) {
                kb[s] = keys[tid + (j + 4) * stride];
                vb[s] = vals[tid + (j + 4) * stride];
            }
            MAIN_ELEM(k4.x, v4.x) MAIN_ELEM(k4.y, v4.y)
            MAIN_ELEM(k4.z, v4.z) MAIN_ELEM(k4.w, v4.w)
        }
    } else {
        // Generic fallback: 1-deep prefetch grid-stride loop.
        int i = tid;
        if (i < n4) {
            int4 k4 = keys[i]; float4 v4 = vals[i];
            for (i += stride; ; i += stride) {
                const bool more = (i < n4);
                int4 nk; float4 nv;
                if (more) { nk = keys[i]; nv = vals[i]; }
                MAIN_ELEM(k4.x, v4.x) MAIN_ELEM(k4.y, v4.y)
                MAIN_ELEM(k4.z, v4.z) MAIN_ELEM(k4.w, v4.w)
                if (!more) break;
                k4 = nk; v4 = nv;
            }
        }
    }
#undef MAIN_ELEM
    __syncthreads();

    // Fold: block cell n = cell>>42, s = (cell&mask) - n*2^24 (exact).
    // Global cell: n*2^44 + (s + n*2^23); per-element |vf| < 2^23 so the low
    // field stays non-negative and additive; totals << 2^44. Exact.
    // Min/max cells untouched by the gate keep identities -> skip.
    const int r  = blockIdx.x & (NREP - 1);
    const int rm = blockIdx.x & (NREP_MM - 1);
    unsigned long long* __restrict__ racc_r  = racc  + (size_t)r  * G;
    unsigned*           __restrict__ rmaxo_r = rmaxo + (size_t)rm * G;
    unsigned*           __restrict__ rminv_r = rminv + (size_t)rm * G;
    for (int k = threadIdx.x; k < G; k += 256) {
        const unsigned long long cell = s_sc[k];
        const unsigned n = (unsigned)(cell >> CNT_SHIFT);
        if (n) {
            const long long s = (long long)(cell & LOW_MASK) - ((long long)n << 24);
            atomicAdd(&racc_r[k],
                      ((unsigned long long)n << GCNT_SHIFT) +
                      (unsigned long long)(s + (long long)n * GSUM_BIAS));
        }
        const unsigned mxv = s_mx[k];
        const unsigned mnv = ~s_mn[k];
        if (mxv) atomicMax(&rmaxo_r[k], mxv);
        if (mnv) atomicMax(&rminv_r[k], mnv);   // min inverted, identity 0
    }
}

// Phase 4: reduce the replicas, write the 5 float32 outputs.
// gid = 1023 - key  =>  slot g = 1023 - k, key_out[g] = k.
__global__ __launch_bounds__(256) void gb_write(
    const unsigned long long* __restrict__ racc,
    const unsigned* __restrict__ rmaxo, const unsigned* __restrict__ rminv,
    float* __restrict__ out)
{
    const int k = blockIdx.x * 256 + threadIdx.x;
    unsigned long long cell = 0ull;
    for (int r = 0; r < NREP; ++r) cell += racc[r * G + k];
    unsigned mx = 0u, mv = 0u;
    for (int r = 0; r < NREP_MM; ++r) {
        mx = max(mx, rmaxo[r * G + k]);
        mv = max(mv, rminv[r * G + k]);
    }
    const unsigned n = (unsigned)(cell >> GCNT_SHIFT);
    const long long s = (long long)(cell & GLOW_MASK) - (long long)n * GSUM_BIAS;
    const float sum = (float)((double)s * (1.0 / (double)SCALEF));
    const int g = (G - 1) - k;
    out[g]         = (float)k;
    out[G + g]     = sum;
    out[2 * G + g] = sum / (float)n;
    out[3 * G + g] = ounmap(~mv);
    out[4 * G + g] = ounmap(mx);
}

extern "C" void kernel_launch(void* const* d_in, const int* in_sizes, int n_in,
                              void* d_out, int out_size, void* d_ws, size_t ws_size,
                              hipStream_t stream) {
    const int4*   keys = (const int4*)d_in[0];
    const float4* vals = (const float4*)d_in[1];
    const int n   = in_sizes[0];
    const int n4  = n / 4;
    int n4w = n4 >> 4;                  // warm slice = first 1/16 (min/max only)
    if (n4w < 1)  n4w = (n4 < 1) ? 0 : n4;
    if (n4w > n4) n4w = n4;

    // Workspace: racc u64[64][G] (512KB) | rmaxo u32[8][G] | rminv u32[8][G] | gate2
    unsigned long long* racc  = (unsigned long long*)d_ws;
    unsigned*           rmaxo = (unsigned*)(racc + (size_t)NREP * G);
    unsigned*           rminv = rmaxo + (size_t)NREP_MM * G;
    unsigned*           gate2 = rminv + (size_t)NREP_MM * G;
    const size_t acc_bytes = (size_t)NREP * G * 8 + 2 * (size_t)NREP_MM * G * 4
                           + 2 * sizeof(unsigned);

    hipMemsetAsync(d_ws, 0, acc_bytes, stream);

    hipLaunchKernelGGL(gb_warm, dim3(512), dim3(256), 0, stream,
                       keys, vals, n4w, rmaxo, rminv);
    hipLaunchKernelGGL(gb_gate, dim3(1), dim3(1024), 0, stream,
                       rmaxo, rminv, gate2);
    hipLaunchKernelGGL(gb_main, dim3(2048), dim3(256), 0, stream,
                       keys, vals, n4, racc, rmaxo, rminv, gate2);
    hipLaunchKernelGGL(gb_write, dim3(G / 256), dim3(256), 0, stream,
                       racc, rmaxo, rminv, (float*)d_out);
}